// Round 10
// baseline (202.279 us; speedup 1.0000x reference)
//
#include <hip/hip_runtime.h>

#define BATCH 1024
#define SEQ   200
#define EMB   128
#define VOCAB 100000

typedef __attribute__((ext_vector_type(8))) short short8;
typedef __attribute__((ext_vector_type(4))) float f32x4;
typedef _Float16 hh2 __attribute__((ext_vector_type(2)));

__device__ __forceinline__ unsigned short f2bf(float x) {
  unsigned u = __float_as_uint(x);
  u += 0x7fffu + ((u >> 16) & 1u);   // RNE
  return (unsigned short)(u >> 16);
}
__device__ __forceinline__ float bf2f(unsigned short b) {
  return __uint_as_float(((unsigned)b) << 16);
}
__device__ __forceinline__ unsigned int packh2(float a, float b) {
  const hh2 p = (hh2){(_Float16)a, (_Float16)b};
  return __builtin_bit_cast(unsigned int, p);
}

// ---------------------------------------------------------------------------
// cvt: Win (fp32) -> bf16, once. 16384 elements.
// ---------------------------------------------------------------------------
__global__ void cvt_bf16(const float* __restrict__ src,
                         unsigned short* __restrict__ dst, int n) {
  int i = blockIdx.x * 256 + threadIdx.x;
  if (i < n) dst[i] = f2bf(src[i]);
}

// ---------------------------------------------------------------------------
// cvt_whq: Wh (fp32 [128][128]) -> Wq (uint4 [16][128]), once.
// Wq[j4*128 + f][q] = pack{ fp16(Wh[f][8*j4+2q]), fp16(Wh[f][8*j4+2q+1]) }.
// rnn10 lane (f) loads Wq[j4*128 + f]: consecutive lanes 16B apart = coalesced.
// ---------------------------------------------------------------------------
__global__ __launch_bounds__(256) void cvt_whq(const float* __restrict__ Wh,
                                               uint4* __restrict__ Wq) {
  const int idx = blockIdx.x * 256 + threadIdx.x;   // 2048 total
  const int j4 = idx >> 7;          // 0..15
  const int f  = idx & 127;
  const float* wr = Wh + (size_t)f * EMB + 8 * j4;
  uint4 o;
  o.x = packh2(wr[0], wr[1]);
  o.y = packh2(wr[2], wr[3]);
  o.z = packh2(wr[4], wr[5]);
  o.w = packh2(wr[6], wr[7]);
  Wq[idx] = o;
}

// ---------------------------------------------------------------------------
// Phase 1 (VERIFIED r2/r5/r7): ip[r*128+f] = sum_e emb[x[r]][e]*Win[f][e],
// bf16 ushort out. 1600 blocks x 256 thr.
// ---------------------------------------------------------------------------
__global__ __launch_bounds__(256) void proj2(
    const int* __restrict__ xidx, const float* __restrict__ emb,
    const unsigned short* __restrict__ Wb, unsigned short* __restrict__ ip)
{
  const int tid = threadIdx.x;
  const int w   = tid >> 6;
  const int l   = tid & 63;
  const int l15 = l & 15;
  const int lhi = l >> 4;

  short8 bfrag[8][4];
#pragma unroll
  for (int nt = 0; nt < 8; ++nt)
#pragma unroll
    for (int kc = 0; kc < 4; ++kc)
      bfrag[nt][kc] = *(const short8*)(Wb + (nt*16 + l15)*EMB + kc*32 + lhi*8);

#pragma unroll
  for (int t = 0; t < 2; ++t) {
    const int m  = blockIdx.x*8 + w*2 + t;
    const int rb = m * 16;
    const long xe = (long)xidx[rb + l15] * EMB;
    short8 afrag[4];
#pragma unroll
    for (int kc = 0; kc < 4; ++kc) {
      const float4* p = (const float4*)(emb + xe + kc*32 + lhi*8);
      float4 a = p[0], b = p[1];
      short8 fr;
      fr[0]=(short)f2bf(a.x); fr[1]=(short)f2bf(a.y);
      fr[2]=(short)f2bf(a.z); fr[3]=(short)f2bf(a.w);
      fr[4]=(short)f2bf(b.x); fr[5]=(short)f2bf(b.y);
      fr[6]=(short)f2bf(b.z); fr[7]=(short)f2bf(b.w);
      afrag[kc] = fr;
    }
    f32x4 acc[8];
#pragma unroll
    for (int nt = 0; nt < 8; ++nt) acc[nt] = (f32x4)(0.0f);
#pragma unroll
    for (int kc = 0; kc < 4; ++kc)
#pragma unroll
      for (int nt = 0; nt < 8; ++nt)
        acc[nt] = __builtin_amdgcn_mfma_f32_16x16x32_bf16(afrag[kc], bfrag[nt][kc], acc[nt], 0, 0, 0);
#pragma unroll
    for (int nt = 0; nt < 8; ++nt)
#pragma unroll
      for (int j = 0; j < 4; ++j)
        ip[(long)(rb + lhi*4 + j)*EMB + nt*16 + l15] = f2bf(acc[nt][j]);
  }
}

// ---------------------------------------------------------------------------
// Phase 2: rnn10 — 2 waves per row, ONE output f per lane. 1024 blocks x
// 128 thr (2048 waves = 2/SIMD -> latency overlap across independent rows).
// Per-lane weights: 16 x uint4 (64 fp16-pairs, consecutive-j pairing =
// r7-verified) — HALF of r8/r9's footprint, loaded as coalesced dwordx4;
// 16 IR values should stay VGPR-resident (r8/r9 post-mortem: regalloc
// refuses >=128-value arrays; ~84-108 is what it tolerates).
// Per step: 1 ushort ip load (2-deep prefetch) + 16 broadcast ds_read_b128
// + 64 fdot2 (4 chains) + tanh + 1 ds_write_b16 + lgkmcnt(0)+s_barrier.
// ---------------------------------------------------------------------------
__global__ __launch_bounds__(128, 2) void rnn10(
    const unsigned short* __restrict__ ip, const uint4* __restrict__ Wq,
    const float* __restrict__ bin, const float* __restrict__ bh,
    float* __restrict__ out)
{
  __shared__ unsigned short hbuf[2][EMB];   // fp16 h, double-buffered (512B)
  __shared__ float red[2];

  const int tid = threadIdx.x;
  const int wv  = tid >> 6;            // 0..1
  const int l   = tid & 63;
  const int f   = wv*64 + l;           // owned output
  const int row = blockIdx.x;

  // weights: wq[c] = pairs j=4c..4c+3 of Wh[f][*]  (elements 8c..8c+7)
  uint4 wq[16];
#pragma unroll
  for (int c = 0; c < 16; ++c) wq[c] = Wq[c*128 + f];
  const float bias = bin[f] + bh[f];

  // h_0 = 0 (128 fp16 = 64 uints)
  if (tid < 64) ((unsigned int*)&hbuf[0][0])[tid] = 0u;
  __syncthreads();

  // ip stream: ushort ip[row][s][f]; prefetch 2 deep
  const unsigned short* ipr = ip + (size_t)row * SEQ * EMB + f;
  unsigned short ic = ipr[0];
  unsigned short in = ipr[EMB];

  float hf = 0.0f;

  for (int s = 0; s < SEQ; ++s) {
    const int sp = (s + 2 < SEQ) ? s + 2 : SEQ - 1;
    const unsigned short pn = ipr[(size_t)sp * EMB];

    // broadcast-read full h (256B = 16 x b128, all lanes same addr)
    const uint4* th = (const uint4*)&hbuf[s & 1][0];

    float a0 = bias + bf2f(ic), a1 = 0.0f, a2 = 0.0f, a3 = 0.0f;
#pragma unroll
    for (int c = 0; c < 16; ++c) {
      const uint4 hc = th[c];    // fp16 elements 8c..8c+7
      a0 = __builtin_amdgcn_fdot2(__builtin_bit_cast(hh2, hc.x),
                                  __builtin_bit_cast(hh2, wq[c].x), a0, false);
      a1 = __builtin_amdgcn_fdot2(__builtin_bit_cast(hh2, hc.y),
                                  __builtin_bit_cast(hh2, wq[c].y), a1, false);
      a2 = __builtin_amdgcn_fdot2(__builtin_bit_cast(hh2, hc.z),
                                  __builtin_bit_cast(hh2, wq[c].z), a2, false);
      a3 = __builtin_amdgcn_fdot2(__builtin_bit_cast(hh2, hc.w),
                                  __builtin_bit_cast(hh2, wq[c].w), a3, false);
    }
    const float v = (a0 + a1) + (a2 + a3);

    // tanh (proven path)
    const float e2 = __expf(2.0f * v);
    hf = 1.0f - __fdividef(2.0f, e2 + 1.0f);

    // write h[f] fp16 (64 lanes x b16, 2B stride = 2-way bank = free)
    hbuf[(s + 1) & 1][f] = __builtin_bit_cast(unsigned short, (_Float16)hf);

    ic = in;
    in = pn;

    // both waves' h writes visible; ip prefetch stays in flight (no vmcnt)
    asm volatile("s_waitcnt lgkmcnt(0)\n\ts_barrier" ::: "memory");
  }

  // L2 normalize: row split across the 2 waves
  float pj = hf * hf;
#pragma unroll
  for (int off = 1; off < 64; off <<= 1) pj += __shfl_xor(pj, off, 64);
  if (l == 0) red[wv] = pj;
  __syncthreads();
  const float inv = 1.0f / fmaxf(sqrtf(red[0] + red[1]), 1e-12f);
  out[(size_t)row*EMB + f] = hf * inv;
}

// ---------------------------------------------------------------------------
// Fallback (small ws): round-1 VALU recurrence (known-correct, no scratch).
// ---------------------------------------------------------------------------
__global__ __launch_bounds__(512) void rnn_fused(
    const int* __restrict__ xidx, const float* __restrict__ emb,
    const float* __restrict__ Win, const float* __restrict__ bin,
    const float* __restrict__ Wh,  const float* __restrict__ bh,
    float* __restrict__ out)
{
  __shared__ float h_lds[4][EMB];
  __shared__ float part[8][4][EMB];
  __shared__ float emb_lds[2][4][EMB];
  __shared__ int   x_lds[4][SEQ];
  __shared__ float red[8];

  const int t   = threadIdx.x;
  const int f0  = (t & 63) * 2;
  const int eg  = t >> 6;
  const int e0  = eg * 16;
  const int b0  = blockIdx.x * 4;
  const int row = t >> 7;
  const int ff  = t & 127;

  float wh0[16], wh1[16], wi0[16], wi1[16];
  {
    const float* p0 = Wh + f0*EMB + e0;
    const float* p1 = Wh + (f0+1)*EMB + e0;
    const float* q0 = Win + f0*EMB + e0;
    const float* q1 = Win + (f0+1)*EMB + e0;
#pragma unroll
    for (int q = 0; q < 4; ++q) {
      float4 a = ((const float4*)p0)[q];
      wh0[4*q+0]=a.x; wh0[4*q+1]=a.y; wh0[4*q+2]=a.z; wh0[4*q+3]=a.w;
      float4 b = ((const float4*)p1)[q];
      wh1[4*q+0]=b.x; wh1[4*q+1]=b.y; wh1[4*q+2]=b.z; wh1[4*q+3]=b.w;
      float4 c = ((const float4*)q0)[q];
      wi0[4*q+0]=c.x; wi0[4*q+1]=c.y; wi0[4*q+2]=c.z; wi0[4*q+3]=c.w;
      float4 d = ((const float4*)q1)[q];
      wi1[4*q+0]=d.x; wi1[4*q+1]=d.y; wi1[4*q+2]=d.z; wi1[4*q+3]=d.w;
    }
  }
  const float bc = bin[ff] + bh[ff];
  h_lds[row][ff] = 0.0f;
  for (int i = t; i < 4*SEQ; i += 512)
    x_lds[i / SEQ][i % SEQ] = xidx[(b0 + i/SEQ)*SEQ + (i % SEQ)];
  __syncthreads();
  emb_lds[0][row][ff] = emb[(long)x_lds[row][0]*EMB + ff];
  __syncthreads();

  int cur = 0;
  for (int s = 0; s < SEQ; ++s) {
    float nxt = 0.0f;
    if (s + 1 < SEQ) nxt = emb[(long)x_lds[row][s+1]*EMB + ff];
    float pa0[4], pa1[4];
#pragma unroll
    for (int rq = 0; rq < 4; ++rq) { pa0[rq] = 0.0f; pa1[rq] = 0.0f; }
#pragma unroll
    for (int rq = 0; rq < 4; ++rq) {
      const float4* hp  = (const float4*)&h_lds[rq][e0];
      const float4* epv = (const float4*)&emb_lds[cur][rq][e0];
#pragma unroll
      for (int q = 0; q < 4; ++q) {
        float4 hv = hp[q], ev = epv[q];
        pa0[rq] = fmaf(hv.x, wh0[4*q+0], pa0[rq]); pa0[rq] = fmaf(hv.y, wh0[4*q+1], pa0[rq]);
        pa0[rq] = fmaf(hv.z, wh0[4*q+2], pa0[rq]); pa0[rq] = fmaf(hv.w, wh0[4*q+3], pa0[rq]);
        pa1[rq] = fmaf(hv.x, wh1[4*q+0], pa1[rq]); pa1[rq] = fmaf(hv.y, wh1[4*q+1], pa1[rq]);
        pa1[rq] = fmaf(hv.z, wh1[4*q+2], pa1[rq]); pa1[rq] = fmaf(hv.w, wh1[4*q+3], pa1[rq]);
        pa0[rq] = fmaf(ev.x, wi0[4*q+0], pa0[rq]); pa0[rq] = fmaf(ev.y, wi0[4*q+1], pa0[rq]);
        pa0[rq] = fmaf(ev.z, wi0[4*q+2], pa0[rq]); pa0[rq] = fmaf(ev.w, wi0[4*q+3], pa0[rq]);
        pa1[rq] = fmaf(ev.x, wi1[4*q+0], pa1[rq]); pa1[rq] = fmaf(ev.y, wi1[4*q+1], pa1[rq]);
        pa1[rq] = fmaf(ev.z, wi1[4*q+2], pa1[rq]); pa1[rq] = fmaf(ev.w, wi1[4*q+3], pa1[rq]);
      }
    }
#pragma unroll
    for (int rq = 0; rq < 4; ++rq) {
      part[eg][rq][f0]   = pa0[rq];
      part[eg][rq][f0+1] = pa1[rq];
    }
    __syncthreads();
    float acc = bc;
#pragma unroll
    for (int g = 0; g < 8; ++g) acc += part[g][row][ff];
    float hn = tanhf(acc);
    if (s + 1 < SEQ) emb_lds[cur ^ 1][row][ff] = nxt;
    h_lds[row][ff] = hn;
    __syncthreads();
    cur ^= 1;
  }
  float hv = h_lds[row][ff];
  float sq = hv * hv;
#pragma unroll
  for (int off = 32; off > 0; off >>= 1) sq += __shfl_xor(sq, off, 64);
  if ((t & 63) == 0) red[t >> 6] = sq;
  __syncthreads();
  float nrm = sqrtf(red[row*2] + red[row*2 + 1]);
  out[(b0 + row)*EMB + ff] = hv / fmaxf(nrm, 1e-12f);
}

// ---------------------------------------------------------------------------
extern "C" void kernel_launch(void* const* d_in, const int* in_sizes, int n_in,
                              void* d_out, int out_size, void* d_ws, size_t ws_size,
                              hipStream_t stream) {
  const int*   x    = (const int*)  d_in[0];
  const float* emb  = (const float*)d_in[1];
  const float* Win  = (const float*)d_in[2];
  const float* bin  = (const float*)d_in[3];
  const float* Wh   = (const float*)d_in[4];
  const float* bh   = (const float*)d_in[5];
  float* out = (float*)d_out;

  const size_t ip_bytes = (size_t)BATCH * SEQ * EMB * sizeof(unsigned short); // 52.4 MB
  const size_t wb_bytes = (size_t)EMB * EMB * sizeof(unsigned short);         // 32 KB
  const size_t wq_bytes = (size_t)16 * 128 * sizeof(uint4);                   // 32 KB
  const size_t need     = ip_bytes + wb_bytes + wq_bytes;
  if (ws_size >= need) {
    unsigned short* ip = (unsigned short*)d_ws;
    unsigned short* Wb = (unsigned short*)((char*)d_ws + ip_bytes);
    uint4*          Wq = (uint4*)((char*)d_ws + ip_bytes + wb_bytes);
    cvt_bf16<<<(EMB*EMB + 255)/256, 256, 0, stream>>>(Win, Wb, EMB*EMB);
    cvt_whq<<<8, 256, 0, stream>>>(Wh, Wq);
    proj2<<<(BATCH*SEQ)/128, 256, 0, stream>>>(x, emb, Wb, ip);
    rnn10<<<BATCH, 128, 0, stream>>>(ip, Wq, bin, bh, out);
  } else {
    rnn_fused<<<BATCH/4, 512, 0, stream>>>(x, emb, Win, bin, Wh, bh, out);
  }
}

// Round 11
// 152.311 us; speedup vs baseline: 1.3281x; 1.3281x over previous
//
#include <hip/hip_runtime.h>

#define BATCH 1024
#define SEQ   200
#define EMB   128
#define VOCAB 100000

typedef __attribute__((ext_vector_type(8))) short short8;
typedef __attribute__((ext_vector_type(4))) float f32x4;
typedef _Float16 hh2 __attribute__((ext_vector_type(2)));

__device__ __forceinline__ unsigned short f2bf(float x) {
  unsigned u = __float_as_uint(x);
  u += 0x7fffu + ((u >> 16) & 1u);   // RNE
  return (unsigned short)(u >> 16);
}
__device__ __forceinline__ float bf2f(unsigned short b) {
  return __uint_as_float(((unsigned)b) << 16);
}
__device__ __forceinline__ unsigned int packh2(float a, float b) {
  const hh2 p = (hh2){(_Float16)a, (_Float16)b};
  return __builtin_bit_cast(unsigned int, p);
}

// ---------------------------------------------------------------------------
// cvt: Win (fp32) -> bf16, once. 16384 elements.
// ---------------------------------------------------------------------------
__global__ void cvt_bf16(const float* __restrict__ src,
                         unsigned short* __restrict__ dst, int n) {
  int i = blockIdx.x * 256 + threadIdx.x;
  if (i < n) dst[i] = f2bf(src[i]);
}

// ---------------------------------------------------------------------------
// cvt_w4: Wh (fp32 [128][128]) -> W4 (uint4 [16][128]), once.
// W4[c*128 + f] = 4 fp16-pairs { {Wh[f][4c+q], Wh[f][4c+64+q]} : q=0..3 }.
// Pairing {j, j+64} matches the h-pair and ip-pair layout (r8-verified).
// Lane f reads W4[c*128 + f]: consecutive lanes 16B apart = coalesced.
// ---------------------------------------------------------------------------
__global__ __launch_bounds__(256) void cvt_w4(const float* __restrict__ Wh,
                                              uint4* __restrict__ W4) {
  const int idx = blockIdx.x * 256 + threadIdx.x;   // 2048 total
  const int c = idx >> 7;           // 0..15
  const int f = idx & 127;
  const float* wr = Wh + (size_t)f * EMB;
  uint4 o;
  o.x = packh2(wr[4*c + 0], wr[4*c + 64]);
  o.y = packh2(wr[4*c + 1], wr[4*c + 65]);
  o.z = packh2(wr[4*c + 2], wr[4*c + 66]);
  o.w = packh2(wr[4*c + 3], wr[4*c + 67]);
  W4[idx] = o;
}

// ---------------------------------------------------------------------------
// Phase 1 (r2-verified MFMA core; r8/r9-verified pairing): input projection,
// storing PAIRED bf16: ipP[r*64 + q] = { bf16(ip[r][q]), bf16(ip[r][q+64]) }.
// ---------------------------------------------------------------------------
__global__ __launch_bounds__(256) void proj2(
    const int* __restrict__ xidx, const float* __restrict__ emb,
    const unsigned short* __restrict__ Wb, unsigned int* __restrict__ ipP)
{
  const int tid = threadIdx.x;
  const int w   = tid >> 6;
  const int l   = tid & 63;
  const int l15 = l & 15;
  const int lhi = l >> 4;

  short8 bfrag[8][4];
#pragma unroll
  for (int nt = 0; nt < 8; ++nt)
#pragma unroll
    for (int kc = 0; kc < 4; ++kc)
      bfrag[nt][kc] = *(const short8*)(Wb + (nt*16 + l15)*EMB + kc*32 + lhi*8);

#pragma unroll
  for (int t = 0; t < 2; ++t) {
    const int m  = blockIdx.x*8 + w*2 + t;
    const int rb = m * 16;
    const long xe = (long)xidx[rb + l15] * EMB;
    short8 afrag[4];
#pragma unroll
    for (int kc = 0; kc < 4; ++kc) {
      const float4* p = (const float4*)(emb + xe + kc*32 + lhi*8);
      float4 a = p[0], b = p[1];
      short8 fr;
      fr[0]=(short)f2bf(a.x); fr[1]=(short)f2bf(a.y);
      fr[2]=(short)f2bf(a.z); fr[3]=(short)f2bf(a.w);
      fr[4]=(short)f2bf(b.x); fr[5]=(short)f2bf(b.y);
      fr[6]=(short)f2bf(b.z); fr[7]=(short)f2bf(b.w);
      afrag[kc] = fr;
    }
    f32x4 acc[8];
#pragma unroll
    for (int nt = 0; nt < 8; ++nt) acc[nt] = (f32x4)(0.0f);
#pragma unroll
    for (int kc = 0; kc < 4; ++kc)
#pragma unroll
      for (int nt = 0; nt < 8; ++nt)
        acc[nt] = __builtin_amdgcn_mfma_f32_16x16x32_bf16(afrag[kc], bfrag[nt][kc], acc[nt], 0, 0, 0);
#pragma unroll
    for (int nt = 0; nt < 4; ++nt)
#pragma unroll
      for (int j = 0; j < 4; ++j) {
        const unsigned int u = (unsigned)f2bf(acc[nt][j])
                             | ((unsigned)f2bf(acc[nt+4][j]) << 16);
        ipP[(long)(rb + lhi*4 + j)*64 + nt*16 + l15] = u;
      }
  }
}

// ---------------------------------------------------------------------------
// Phase 2: rnn11 — rnn8 structure + VOLATILE-ASM weight loads (single change).
// r8/r9/r10 post-mortem: plain loads of per-lane weight arrays are always
// re-executed inside the loop by the compiler (VGPR 84/84/44 vs needed
// 128/128/64). Volatile asm global_load_dwordx4 cannot be rematerialized,
// sunk, or duplicated -> the 32 result tuples (128 VGPRs) must stay live.
// Completion: __syncthreads() after the batch (compiler emits full vmcnt(0)
// drain before s_barrier; loop body cannot hoist above it).
// Everything else bit-identical to rnn8 (best measured: 108 us).
// ---------------------------------------------------------------------------
__global__ __launch_bounds__(256, 1) void rnn11(
    const unsigned int* __restrict__ ipP, const uint4* __restrict__ W4,
    const float* __restrict__ bin, const float* __restrict__ bh,
    float* __restrict__ out)
{
  __shared__ unsigned int hb[4][2][64];   // [wave][buf][64 uints = h pairs]

  const int tid = threadIdx.x;
  const int w   = tid >> 6;            // wave = local row 0..3
  const int l   = tid & 63;
  const int row = blockIdx.x*4 + w;    // global batch row

  // h_0 = 0 (before weight loads; drained by the same __syncthreads)
  hb[w][0][l] = 0u;

  // weights for outputs f=l and f=l+64, as 16 uint4 each (pairs {j, j+64}).
  // Volatile asm: cannot be sunk into the loop or re-executed.
  uint4 wq0[16], wq1[16];
#pragma unroll
  for (int c = 0; c < 16; ++c) {
    const uint4* a0 = W4 + c*128 + l;
    const uint4* a1 = W4 + c*128 + 64 + l;
    asm volatile("global_load_dwordx4 %0, %1, off" : "=v"(wq0[c]) : "v"(a0));
    asm volatile("global_load_dwordx4 %0, %1, off" : "=v"(wq1[c]) : "v"(a1));
  }
  __syncthreads();   // full vmcnt/lgkmcnt drain: weights resident, h0 visible

  const float bias0 = bin[l]      + bh[l];
  const float bias1 = bin[l + 64] + bh[l + 64];

  // ip stream: uint pair {ip[row][s][l], ip[row][s][l+64]}; prefetch 2 deep
  const unsigned int* ipp = ipP + (size_t)row * SEQ * 64 + l;
  unsigned int ic = ipp[0];
  unsigned int in = ipp[64];

  float hf0 = 0.0f, hf1 = 0.0f;

  for (int s = 0; s < SEQ; ++s) {
    // issue ip load for s+2 (stays in flight; compiler counts vmcnt)
    const int sp = (s + 2 < SEQ) ? s + 2 : SEQ - 1;
    const unsigned int pn = ipp[(size_t)sp * 64];

    // broadcast-read this wave's h (256B = 16 x b128, all lanes same addr)
    const uint4* th = (const uint4*)&hb[w][s & 1][0];

    float a0[4], a1[4];
    a0[0] = bias0 + __uint_as_float(ic << 16);
    a1[0] = bias1 + __uint_as_float(ic & 0xffff0000u);
    a0[1] = a0[2] = a0[3] = 0.0f;
    a1[1] = a1[2] = a1[3] = 0.0f;

#pragma unroll
    for (int c = 0; c < 16; ++c) {
      const uint4 hc = th[c];                         // pairs j=4c..4c+3
      const hh2 hx = __builtin_bit_cast(hh2, hc.x);
      const hh2 hy = __builtin_bit_cast(hh2, hc.y);
      const hh2 hz = __builtin_bit_cast(hh2, hc.z);
      const hh2 hw = __builtin_bit_cast(hh2, hc.w);
      const int k = c & 3;
      a0[k] = __builtin_amdgcn_fdot2(hx, __builtin_bit_cast(hh2, wq0[c].x), a0[k], false);
      a0[k] = __builtin_amdgcn_fdot2(hy, __builtin_bit_cast(hh2, wq0[c].y), a0[k], false);
      a0[k] = __builtin_amdgcn_fdot2(hz, __builtin_bit_cast(hh2, wq0[c].z), a0[k], false);
      a0[k] = __builtin_amdgcn_fdot2(hw, __builtin_bit_cast(hh2, wq0[c].w), a0[k], false);
      a1[k] = __builtin_amdgcn_fdot2(hx, __builtin_bit_cast(hh2, wq1[c].x), a1[k], false);
      a1[k] = __builtin_amdgcn_fdot2(hy, __builtin_bit_cast(hh2, wq1[c].y), a1[k], false);
      a1[k] = __builtin_amdgcn_fdot2(hz, __builtin_bit_cast(hh2, wq1[c].z), a1[k], false);
      a1[k] = __builtin_amdgcn_fdot2(hw, __builtin_bit_cast(hh2, wq1[c].w), a1[k], false);
    }
    const float v0 = (a0[0] + a0[1]) + (a0[2] + a0[3]);
    const float v1 = (a1[0] + a1[1]) + (a1[2] + a1[3]);

    // tanh (proven path)
    const float e0 = __expf(2.0f * v0);
    hf0 = 1.0f - __fdividef(2.0f, e0 + 1.0f);
    const float e1 = __expf(2.0f * v1);
    hf1 = 1.0f - __fdividef(2.0f, e1 + 1.0f);

    // write next h pair (fp16 RNE), one uint per lane, conflict-free.
    // Intra-wave RAW on LDS: per-wave DS ops are ordered; compiler inserts
    // the lgkmcnt before next iteration's reads. No barrier needed.
    hb[w][(s + 1) & 1][l] = packh2(hf0, hf1);

    ic = in;
    in = pn;
  }

  // L2 normalize: whole row in this wave (2 values/lane)
  float pj = hf0*hf0 + hf1*hf1;
#pragma unroll
  for (int off = 1; off < 64; off <<= 1) pj += __shfl_xor(pj, off, 64);
  const float inv = 1.0f / fmaxf(sqrtf(pj), 1e-12f);
  out[(size_t)row*EMB + l]      = hf0 * inv;
  out[(size_t)row*EMB + 64 + l] = hf1 * inv;
}

// ---------------------------------------------------------------------------
// Fallback (small ws): round-1 VALU recurrence (known-correct, no scratch).
// ---------------------------------------------------------------------------
__global__ __launch_bounds__(512) void rnn_fused(
    const int* __restrict__ xidx, const float* __restrict__ emb,
    const float* __restrict__ Win, const float* __restrict__ bin,
    const float* __restrict__ Wh,  const float* __restrict__ bh,
    float* __restrict__ out)
{
  __shared__ float h_lds[4][EMB];
  __shared__ float part[8][4][EMB];
  __shared__ float emb_lds[2][4][EMB];
  __shared__ int   x_lds[4][SEQ];
  __shared__ float red[8];

  const int t   = threadIdx.x;
  const int f0  = (t & 63) * 2;
  const int eg  = t >> 6;
  const int e0  = eg * 16;
  const int b0  = blockIdx.x * 4;
  const int row = t >> 7;
  const int ff  = t & 127;

  float wh0[16], wh1[16], wi0[16], wi1[16];
  {
    const float* p0 = Wh + f0*EMB + e0;
    const float* p1 = Wh + (f0+1)*EMB + e0;
    const float* q0 = Win + f0*EMB + e0;
    const float* q1 = Win + (f0+1)*EMB + e0;
#pragma unroll
    for (int q = 0; q < 4; ++q) {
      float4 a = ((const float4*)p0)[q];
      wh0[4*q+0]=a.x; wh0[4*q+1]=a.y; wh0[4*q+2]=a.z; wh0[4*q+3]=a.w;
      float4 b = ((const float4*)p1)[q];
      wh1[4*q+0]=b.x; wh1[4*q+1]=b.y; wh1[4*q+2]=b.z; wh1[4*q+3]=b.w;
      float4 c = ((const float4*)q0)[q];
      wi0[4*q+0]=c.x; wi0[4*q+1]=c.y; wi0[4*q+2]=c.z; wi0[4*q+3]=c.w;
      float4 d = ((const float4*)q1)[q];
      wi1[4*q+0]=d.x; wi1[4*q+1]=d.y; wi1[4*q+2]=d.z; wi1[4*q+3]=d.w;
    }
  }
  const float bc = bin[ff] + bh[ff];
  h_lds[row][ff] = 0.0f;
  for (int i = t; i < 4*SEQ; i += 512)
    x_lds[i / SEQ][i % SEQ] = xidx[(b0 + i/SEQ)*SEQ + (i % SEQ)];
  __syncthreads();
  emb_lds[0][row][ff] = emb[(long)x_lds[row][0]*EMB + ff];
  __syncthreads();

  int cur = 0;
  for (int s = 0; s < SEQ; ++s) {
    float nxt = 0.0f;
    if (s + 1 < SEQ) nxt = emb[(long)x_lds[row][s+1]*EMB + ff];
    float pa0[4], pa1[4];
#pragma unroll
    for (int rq = 0; rq < 4; ++rq) { pa0[rq] = 0.0f; pa1[rq] = 0.0f; }
#pragma unroll
    for (int rq = 0; rq < 4; ++rq) {
      const float4* hp  = (const float4*)&h_lds[rq][e0];
      const float4* epv = (const float4*)&emb_lds[cur][rq][e0];
#pragma unroll
      for (int q = 0; q < 4; ++q) {
        float4 hv = hp[q], ev = epv[q];
        pa0[rq] = fmaf(hv.x, wh0[4*q+0], pa0[rq]); pa0[rq] = fmaf(hv.y, wh0[4*q+1], pa0[rq]);
        pa0[rq] = fmaf(hv.z, wh0[4*q+2], pa0[rq]); pa0[rq] = fmaf(hv.w, wh0[4*q+3], pa0[rq]);
        pa1[rq] = fmaf(hv.x, wh1[4*q+0], pa1[rq]); pa1[rq] = fmaf(hv.y, wh1[4*q+1], pa1[rq]);
        pa1[rq] = fmaf(hv.z, wh1[4*q+2], pa1[rq]); pa1[rq] = fmaf(hv.w, wh1[4*q+3], pa1[rq]);
        pa0[rq] = fmaf(ev.x, wi0[4*q+0], pa0[rq]); pa0[rq] = fmaf(ev.y, wi0[4*q+1], pa0[rq]);
        pa0[rq] = fmaf(ev.z, wi0[4*q+2], pa0[rq]); pa0[rq] = fmaf(ev.w, wi0[4*q+3], pa0[rq]);
        pa1[rq] = fmaf(ev.x, wi1[4*q+0], pa1[rq]); pa1[rq] = fmaf(ev.y, wi1[4*q+1], pa1[rq]);
        pa1[rq] = fmaf(ev.z, wi1[4*q+2], pa1[rq]); pa1[rq] = fmaf(ev.w, wi1[4*q+3], pa1[rq]);
      }
    }
#pragma unroll
    for (int rq = 0; rq < 4; ++rq) {
      part[eg][rq][f0]   = pa0[rq];
      part[eg][rq][f0+1] = pa1[rq];
    }
    __syncthreads();
    float acc = bc;
#pragma unroll
    for (int g = 0; g < 8; ++g) acc += part[g][row][ff];
    float hn = tanhf(acc);
    if (s + 1 < SEQ) emb_lds[cur ^ 1][row][ff] = nxt;
    h_lds[row][ff] = hn;
    __syncthreads();
    cur ^= 1;
  }
  float hv = h_lds[row][ff];
  float sq = hv * hv;
#pragma unroll
  for (int off = 32; off > 0; off >>= 1) sq += __shfl_xor(sq, off, 64);
  if ((t & 63) == 0) red[t >> 6] = sq;
  __syncthreads();
  float nrm = sqrtf(red[row*2] + red[row*2 + 1]);
  out[(b0 + row)*EMB + ff] = hv / fmaxf(nrm, 1e-12f);
}

// ---------------------------------------------------------------------------
extern "C" void kernel_launch(void* const* d_in, const int* in_sizes, int n_in,
                              void* d_out, int out_size, void* d_ws, size_t ws_size,
                              hipStream_t stream) {
  const int*   x    = (const int*)  d_in[0];
  const float* emb  = (const float*)d_in[1];
  const float* Win  = (const float*)d_in[2];
  const float* bin  = (const float*)d_in[3];
  const float* Wh   = (const float*)d_in[4];
  const float* bh   = (const float*)d_in[5];
  float* out = (float*)d_out;

  const size_t ip_bytes = (size_t)BATCH * SEQ * 64 * sizeof(unsigned int); // 52.4 MB
  const size_t wb_bytes = (size_t)EMB * EMB * sizeof(unsigned short);      // 32 KB
  const size_t w4_bytes = (size_t)16 * 128 * sizeof(uint4);                // 32 KB
  const size_t need     = ip_bytes + wb_bytes + w4_bytes;
  if (ws_size >= need) {
    unsigned int*   ipP = (unsigned int*)d_ws;
    unsigned short* Wb  = (unsigned short*)((char*)d_ws + ip_bytes);
    uint4*          W4  = (uint4*)((char*)d_ws + ip_bytes + wb_bytes);
    cvt_bf16<<<(EMB*EMB + 255)/256, 256, 0, stream>>>(Win, Wb, EMB*EMB);
    cvt_w4<<<8, 256, 0, stream>>>(Wh, W4);
    proj2<<<(BATCH*SEQ)/128, 256, 0, stream>>>(x, emb, Wb, ipP);
    rnn11<<<BATCH/4, 256, 0, stream>>>(ipP, W4, bin, bh, out);
  } else {
    rnn_fused<<<BATCH/4, 512, 0, stream>>>(x, emb, Win, bin, Wh, bh, out);
  }
}

// Round 12
// 151.877 us; speedup vs baseline: 1.3319x; 1.0029x over previous
//
#include <hip/hip_runtime.h>

#define BATCH 1024
#define SEQ   200
#define EMB   128
#define VOCAB 100000

typedef __attribute__((ext_vector_type(8))) short short8;
typedef __attribute__((ext_vector_type(4))) float f32x4;
typedef _Float16 hh2 __attribute__((ext_vector_type(2)));

__device__ __forceinline__ unsigned short f2bf(float x) {
  unsigned u = __float_as_uint(x);
  u += 0x7fffu + ((u >> 16) & 1u);   // RNE
  return (unsigned short)(u >> 16);
}
__device__ __forceinline__ float bf2f(unsigned short b) {
  return __uint_as_float(((unsigned)b) << 16);
}
__device__ __forceinline__ unsigned int packh2(float a, float b) {
  const hh2 p = (hh2){(_Float16)a, (_Float16)b};
  return __builtin_bit_cast(unsigned int, p);
}
__device__ __forceinline__ float fd(unsigned int h2, unsigned int w2, float acc) {
  return __builtin_amdgcn_fdot2(__builtin_bit_cast(hh2, h2),
                                __builtin_bit_cast(hh2, w2), acc, false);
}

// ---------------------------------------------------------------------------
// cvt: Win (fp32) -> bf16, once.
// ---------------------------------------------------------------------------
__global__ void cvt_bf16(const float* __restrict__ src,
                         unsigned short* __restrict__ dst, int n) {
  int i = blockIdx.x * 256 + threadIdx.x;
  if (i < n) dst[i] = f2bf(src[i]);
}

// ---------------------------------------------------------------------------
// cvt_w4: Wh -> W4 (uint4 [16][128]); W4[c*128+f] = pairs {4c+q, 4c+64+q}.
// (r11-verified pairing.)
// ---------------------------------------------------------------------------
__global__ __launch_bounds__(256) void cvt_w4(const float* __restrict__ Wh,
                                              uint4* __restrict__ W4) {
  const int idx = blockIdx.x * 256 + threadIdx.x;   // 2048 total
  const int c = idx >> 7;
  const int f = idx & 127;
  const float* wr = Wh + (size_t)f * EMB;
  uint4 o;
  o.x = packh2(wr[4*c + 0], wr[4*c + 64]);
  o.y = packh2(wr[4*c + 1], wr[4*c + 65]);
  o.z = packh2(wr[4*c + 2], wr[4*c + 66]);
  o.w = packh2(wr[4*c + 3], wr[4*c + 67]);
  W4[idx] = o;
}

// ---------------------------------------------------------------------------
// Phase 1 (verified r2..r11): input projection, paired bf16 output.
// ---------------------------------------------------------------------------
__global__ __launch_bounds__(256) void proj2(
    const int* __restrict__ xidx, const float* __restrict__ emb,
    const unsigned short* __restrict__ Wb, unsigned int* __restrict__ ipP)
{
  const int tid = threadIdx.x;
  const int w   = tid >> 6;
  const int l   = tid & 63;
  const int l15 = l & 15;
  const int lhi = l >> 4;

  short8 bfrag[8][4];
#pragma unroll
  for (int nt = 0; nt < 8; ++nt)
#pragma unroll
    for (int kc = 0; kc < 4; ++kc)
      bfrag[nt][kc] = *(const short8*)(Wb + (nt*16 + l15)*EMB + kc*32 + lhi*8);

#pragma unroll
  for (int t = 0; t < 2; ++t) {
    const int m  = blockIdx.x*8 + w*2 + t;
    const int rb = m * 16;
    const long xe = (long)xidx[rb + l15] * EMB;
    short8 afrag[4];
#pragma unroll
    for (int kc = 0; kc < 4; ++kc) {
      const float4* p = (const float4*)(emb + xe + kc*32 + lhi*8);
      float4 a = p[0], b = p[1];
      short8 fr;
      fr[0]=(short)f2bf(a.x); fr[1]=(short)f2bf(a.y);
      fr[2]=(short)f2bf(a.z); fr[3]=(short)f2bf(a.w);
      fr[4]=(short)f2bf(b.x); fr[5]=(short)f2bf(b.y);
      fr[6]=(short)f2bf(b.z); fr[7]=(short)f2bf(b.w);
      afrag[kc] = fr;
    }
    f32x4 acc[8];
#pragma unroll
    for (int nt = 0; nt < 8; ++nt) acc[nt] = (f32x4)(0.0f);
#pragma unroll
    for (int kc = 0; kc < 4; ++kc)
#pragma unroll
      for (int nt = 0; nt < 8; ++nt)
        acc[nt] = __builtin_amdgcn_mfma_f32_16x16x32_bf16(afrag[kc], bfrag[nt][kc], acc[nt], 0, 0, 0);
#pragma unroll
    for (int nt = 0; nt < 4; ++nt)
#pragma unroll
      for (int j = 0; j < 4; ++j) {
        const unsigned int u = (unsigned)f2bf(acc[nt][j])
                             | ((unsigned)f2bf(acc[nt+4][j]) << 16);
        ipP[(long)(rb + lhi*4 + j)*64 + nt*16 + l15] = u;
      }
  }
}

// ---------------------------------------------------------------------------
// Phase 2: rnn12 — rnn8 structure, weights in 32 NAMED uint4 variables.
// r8-r11 post-mortem: per-lane weight ARRAYS (even static-indexed, even
// volatile-asm-loaded) never pass SROA -> they live in scratch; the loop
// reloads 512B/lane/step from scratch (invisible in FETCH, eats issue).
// Named scalars always mem2reg -> 128 VGPRs of weights genuinely resident
// (budget 256 arch VGPRs @ launch_bounds(256,1); est. use ~190).
// Everything else bit-identical to rnn8/rnn11 (verified math & layouts).
// ---------------------------------------------------------------------------
__global__ __launch_bounds__(256, 1) void rnn12(
    const unsigned int* __restrict__ ipP, const uint4* __restrict__ W4,
    const float* __restrict__ bin, const float* __restrict__ bh,
    float* __restrict__ out)
{
  __shared__ unsigned int hb[4][2][64];   // [wave][buf][64 h-pair uints]

  const int tid = threadIdx.x;
  const int w   = tid >> 6;            // wave = local row 0..3
  const int l   = tid & 63;
  const int row = blockIdx.x*4 + w;    // global batch row

  hb[w][0][l] = 0u;                    // h_0 = 0

  // 32 NAMED weight registers (16 chunks x {f=l, f=l+64}), coalesced loads.
#define WLD(i) \
  const uint4 wa##i = W4[(i)*128 + l]; \
  const uint4 wb##i = W4[(i)*128 + 64 + l];
  WLD(0)  WLD(1)  WLD(2)  WLD(3)  WLD(4)  WLD(5)  WLD(6)  WLD(7)
  WLD(8)  WLD(9)  WLD(10) WLD(11) WLD(12) WLD(13) WLD(14) WLD(15)
#undef WLD

  const float bias0 = bin[l]      + bh[l];
  const float bias1 = bin[l + 64] + bh[l + 64];
  __syncthreads();   // h0 visible (and weight loads drained once)

  // ip stream: uint pair {ip[row][s][l], ip[row][s][l+64]}; prefetch 2 deep
  const unsigned int* ipp = ipP + (size_t)row * SEQ * 64 + l;
  unsigned int ic = ipp[0];
  unsigned int in = ipp[64];

  float hf0 = 0.0f, hf1 = 0.0f;

  for (int s = 0; s < SEQ; ++s) {
    const int sp = (s + 2 < SEQ) ? s + 2 : SEQ - 1;
    const unsigned int pn = ipp[(size_t)sp * 64];

    const uint4* th = (const uint4*)&hb[w][s & 1][0];

    float a00 = bias0 + __uint_as_float(ic << 16);
    float a10 = bias1 + __uint_as_float(ic & 0xffff0000u);
    float a01 = 0.0f, a02 = 0.0f, a03 = 0.0f;
    float a11 = 0.0f, a12 = 0.0f, a13 = 0.0f;

    // 16 chunks: broadcast b128 h read + 8 fdot2, named temps (die fast)
#define STEP(i, K) { \
    const uint4 hc = th[i]; \
    a0##K = fd(hc.x, wa##i.x, a0##K); \
    a0##K = fd(hc.y, wa##i.y, a0##K); \
    a0##K = fd(hc.z, wa##i.z, a0##K); \
    a0##K = fd(hc.w, wa##i.w, a0##K); \
    a1##K = fd(hc.x, wb##i.x, a1##K); \
    a1##K = fd(hc.y, wb##i.y, a1##K); \
    a1##K = fd(hc.z, wb##i.z, a1##K); \
    a1##K = fd(hc.w, wb##i.w, a1##K); }
    STEP(0,0)  STEP(1,1)  STEP(2,2)  STEP(3,3)
    STEP(4,0)  STEP(5,1)  STEP(6,2)  STEP(7,3)
    STEP(8,0)  STEP(9,1)  STEP(10,2) STEP(11,3)
    STEP(12,0) STEP(13,1) STEP(14,2) STEP(15,3)
#undef STEP

    const float v0 = (a00 + a01) + (a02 + a03);
    const float v1 = (a10 + a11) + (a12 + a13);

    // tanh (proven path)
    const float e0 = __expf(2.0f * v0);
    hf0 = 1.0f - __fdividef(2.0f, e0 + 1.0f);
    const float e1 = __expf(2.0f * v1);
    hf1 = 1.0f - __fdividef(2.0f, e1 + 1.0f);

    // next h pair; intra-wave DS ordering, no barrier (r8-verified)
    hb[w][(s + 1) & 1][l] = packh2(hf0, hf1);

    ic = in;
    in = pn;
  }

  // L2 normalize: whole row in this wave (2 values/lane)
  float pj = hf0*hf0 + hf1*hf1;
#pragma unroll
  for (int off = 1; off < 64; off <<= 1) pj += __shfl_xor(pj, off, 64);
  const float inv = 1.0f / fmaxf(sqrtf(pj), 1e-12f);
  out[(size_t)row*EMB + l]      = hf0 * inv;
  out[(size_t)row*EMB + 64 + l] = hf1 * inv;
}

// ---------------------------------------------------------------------------
// Fallback (small ws): round-1 VALU recurrence (known-correct, no scratch).
// ---------------------------------------------------------------------------
__global__ __launch_bounds__(512) void rnn_fused(
    const int* __restrict__ xidx, const float* __restrict__ emb,
    const float* __restrict__ Win, const float* __restrict__ bin,
    const float* __restrict__ Wh,  const float* __restrict__ bh,
    float* __restrict__ out)
{
  __shared__ float h_lds[4][EMB];
  __shared__ float part[8][4][EMB];
  __shared__ float emb_lds[2][4][EMB];
  __shared__ int   x_lds[4][SEQ];
  __shared__ float red[8];

  const int t   = threadIdx.x;
  const int f0  = (t & 63) * 2;
  const int eg  = t >> 6;
  const int e0  = eg * 16;
  const int b0  = blockIdx.x * 4;
  const int row = t >> 7;
  const int ff  = t & 127;

  float wh0[16], wh1[16], wi0[16], wi1[16];
  {
    const float* p0 = Wh + f0*EMB + e0;
    const float* p1 = Wh + (f0+1)*EMB + e0;
    const float* q0 = Win + f0*EMB + e0;
    const float* q1 = Win + (f0+1)*EMB + e0;
#pragma unroll
    for (int q = 0; q < 4; ++q) {
      float4 a = ((const float4*)p0)[q];
      wh0[4*q+0]=a.x; wh0[4*q+1]=a.y; wh0[4*q+2]=a.z; wh0[4*q+3]=a.w;
      float4 b = ((const float4*)p1)[q];
      wh1[4*q+0]=b.x; wh1[4*q+1]=b.y; wh1[4*q+2]=b.z; wh1[4*q+3]=b.w;
      float4 c = ((const float4*)q0)[q];
      wi0[4*q+0]=c.x; wi0[4*q+1]=c.y; wi0[4*q+2]=c.z; wi0[4*q+3]=c.w;
      float4 d = ((const float4*)q1)[q];
      wi1[4*q+0]=d.x; wi1[4*q+1]=d.y; wi1[4*q+2]=d.z; wi1[4*q+3]=d.w;
    }
  }
  const float bc = bin[ff] + bh[ff];
  h_lds[row][ff] = 0.0f;
  for (int i = t; i < 4*SEQ; i += 512)
    x_lds[i / SEQ][i % SEQ] = xidx[(b0 + i/SEQ)*SEQ + (i % SEQ)];
  __syncthreads();
  emb_lds[0][row][ff] = emb[(long)x_lds[row][0]*EMB + ff];
  __syncthreads();

  int cur = 0;
  for (int s = 0; s < SEQ; ++s) {
    float nxt = 0.0f;
    if (s + 1 < SEQ) nxt = emb[(long)x_lds[row][s+1]*EMB + ff];
    float pa0[4], pa1[4];
#pragma unroll
    for (int rq = 0; rq < 4; ++rq) { pa0[rq] = 0.0f; pa1[rq] = 0.0f; }
#pragma unroll
    for (int rq = 0; rq < 4; ++rq) {
      const float4* hp  = (const float4*)&h_lds[rq][e0];
      const float4* epv = (const float4*)&emb_lds[cur][rq][e0];
#pragma unroll
      for (int q = 0; q < 4; ++q) {
        float4 hv = hp[q], ev = epv[q];
        pa0[rq] = fmaf(hv.x, wh0[4*q+0], pa0[rq]); pa0[rq] = fmaf(hv.y, wh0[4*q+1], pa0[rq]);
        pa0[rq] = fmaf(hv.z, wh0[4*q+2], pa0[rq]); pa0[rq] = fmaf(hv.w, wh0[4*q+3], pa0[rq]);
        pa1[rq] = fmaf(hv.x, wh1[4*q+0], pa1[rq]); pa1[rq] = fmaf(hv.y, wh1[4*q+1], pa1[rq]);
        pa1[rq] = fmaf(hv.z, wh1[4*q+2], pa1[rq]); pa1[rq] = fmaf(hv.w, wh1[4*q+3], pa1[rq]);
        pa0[rq] = fmaf(ev.x, wi0[4*q+0], pa0[rq]); pa0[rq] = fmaf(ev.y, wi0[4*q+1], pa0[rq]);
        pa0[rq] = fmaf(ev.z, wi0[4*q+2], pa0[rq]); pa0[rq] = fmaf(ev.w, wi0[4*q+3], pa0[rq]);
        pa1[rq] = fmaf(ev.x, wi1[4*q+0], pa1[rq]); pa1[rq] = fmaf(ev.y, wi1[4*q+1], pa1[rq]);
        pa1[rq] = fmaf(ev.z, wi1[4*q+2], pa1[rq]); pa1[rq] = fmaf(ev.w, wi1[4*q+3], pa1[rq]);
      }
    }
#pragma unroll
    for (int rq = 0; rq < 4; ++rq) {
      part[eg][rq][f0]   = pa0[rq];
      part[eg][rq][f0+1] = pa1[rq];
    }
    __syncthreads();
    float acc = bc;
#pragma unroll
    for (int g = 0; g < 8; ++g) acc += part[g][row][ff];
    float hn = tanhf(acc);
    if (s + 1 < SEQ) emb_lds[cur ^ 1][row][ff] = nxt;
    h_lds[row][ff] = hn;
    __syncthreads();
    cur ^= 1;
  }
  float hv = h_lds[row][ff];
  float sq = hv * hv;
#pragma unroll
  for (int off = 32; off > 0; off >>= 1) sq += __shfl_xor(sq, off, 64);
  if ((t & 63) == 0) red[t >> 6] = sq;
  __syncthreads();
  float nrm = sqrtf(red[row*2] + red[row*2 + 1]);
  out[(b0 + row)*EMB + ff] = hv / fmaxf(nrm, 1e-12f);
}

// ---------------------------------------------------------------------------
extern "C" void kernel_launch(void* const* d_in, const int* in_sizes, int n_in,
                              void* d_out, int out_size, void* d_ws, size_t ws_size,
                              hipStream_t stream) {
  const int*   x    = (const int*)  d_in[0];
  const float* emb  = (const float*)d_in[1];
  const float* Win  = (const float*)d_in[2];
  const float* bin  = (const float*)d_in[3];
  const float* Wh   = (const float*)d_in[4];
  const float* bh   = (const float*)d_in[5];
  float* out = (float*)d_out;

  const size_t ip_bytes = (size_t)BATCH * SEQ * 64 * sizeof(unsigned int); // 52.4 MB
  const size_t wb_bytes = (size_t)EMB * EMB * sizeof(unsigned short);      // 32 KB
  const size_t w4_bytes = (size_t)16 * 128 * sizeof(uint4);                // 32 KB
  const size_t need     = ip_bytes + wb_bytes + w4_bytes;
  if (ws_size >= need) {
    unsigned int*   ipP = (unsigned int*)d_ws;
    unsigned short* Wb  = (unsigned short*)((char*)d_ws + ip_bytes);
    uint4*          W4  = (uint4*)((char*)d_ws + ip_bytes + wb_bytes);
    cvt_bf16<<<(EMB*EMB + 255)/256, 256, 0, stream>>>(Win, Wb, EMB*EMB);
    cvt_w4<<<8, 256, 0, stream>>>(Wh, W4);
    proj2<<<(BATCH*SEQ)/128, 256, 0, stream>>>(x, emb, Wb, ipP);
    rnn12<<<BATCH/4, 256, 0, stream>>>(ipP, W4, bin, bh, out);
  } else {
    rnn_fused<<<BATCH/4, 512, 0, stream>>>(x, emb, Win, bin, Wh, bh, out);
  }
}

// Round 13
// 145.018 us; speedup vs baseline: 1.3948x; 1.0473x over previous
//
#include <hip/hip_runtime.h>

#define BATCH 1024
#define SEQ   200
#define EMB   128
#define VOCAB 100000

typedef __attribute__((ext_vector_type(8))) short short8;
typedef __attribute__((ext_vector_type(4))) float f32x4;
typedef _Float16 hh2 __attribute__((ext_vector_type(2)));

__device__ __forceinline__ unsigned short f2bf(float x) {
  unsigned u = __float_as_uint(x);
  u += 0x7fffu + ((u >> 16) & 1u);   // RNE
  return (unsigned short)(u >> 16);
}
__device__ __forceinline__ float bf2f(unsigned short b) {
  return __uint_as_float(((unsigned)b) << 16);
}
__device__ __forceinline__ unsigned int packh2(float a, float b) {
  const hh2 p = (hh2){(_Float16)a, (_Float16)b};
  return __builtin_bit_cast(unsigned int, p);
}
__device__ __forceinline__ float fd(unsigned int h2, unsigned int w2, float acc) {
  return __builtin_amdgcn_fdot2(__builtin_bit_cast(hh2, h2),
                                __builtin_bit_cast(hh2, w2), acc, false);
}

// ---------------------------------------------------------------------------
// cvt: Win (fp32) -> bf16, once.
// ---------------------------------------------------------------------------
__global__ void cvt_bf16(const float* __restrict__ src,
                         unsigned short* __restrict__ dst, int n) {
  int i = blockIdx.x * 256 + threadIdx.x;
  if (i < n) dst[i] = f2bf(src[i]);
}

// ---------------------------------------------------------------------------
// cvt_w4: Wh -> W4 (uint4 [16][128]); W4[c*128+f] = pairs {4c+q, 4c+64+q}.
// (r11/r12-verified pairing.)
// ---------------------------------------------------------------------------
__global__ __launch_bounds__(256) void cvt_w4(const float* __restrict__ Wh,
                                              uint4* __restrict__ W4) {
  const int idx = blockIdx.x * 256 + threadIdx.x;   // 2048 total
  const int c = idx >> 7;
  const int f = idx & 127;
  const float* wr = Wh + (size_t)f * EMB;
  uint4 o;
  o.x = packh2(wr[4*c + 0], wr[4*c + 64]);
  o.y = packh2(wr[4*c + 1], wr[4*c + 65]);
  o.z = packh2(wr[4*c + 2], wr[4*c + 66]);
  o.w = packh2(wr[4*c + 3], wr[4*c + 67]);
  W4[idx] = o;
}

// ---------------------------------------------------------------------------
// Phase 1 (verified r2..r12): input projection, paired bf16 output.
// ---------------------------------------------------------------------------
__global__ __launch_bounds__(256) void proj2(
    const int* __restrict__ xidx, const float* __restrict__ emb,
    const unsigned short* __restrict__ Wb, unsigned int* __restrict__ ipP)
{
  const int tid = threadIdx.x;
  const int w   = tid >> 6;
  const int l   = tid & 63;
  const int l15 = l & 15;
  const int lhi = l >> 4;

  short8 bfrag[8][4];
#pragma unroll
  for (int nt = 0; nt < 8; ++nt)
#pragma unroll
    for (int kc = 0; kc < 4; ++kc)
      bfrag[nt][kc] = *(const short8*)(Wb + (nt*16 + l15)*EMB + kc*32 + lhi*8);

#pragma unroll
  for (int t = 0; t < 2; ++t) {
    const int m  = blockIdx.x*8 + w*2 + t;
    const int rb = m * 16;
    const long xe = (long)xidx[rb + l15] * EMB;
    short8 afrag[4];
#pragma unroll
    for (int kc = 0; kc < 4; ++kc) {
      const float4* p = (const float4*)(emb + xe + kc*32 + lhi*8);
      float4 a = p[0], b = p[1];
      short8 fr;
      fr[0]=(short)f2bf(a.x); fr[1]=(short)f2bf(a.y);
      fr[2]=(short)f2bf(a.z); fr[3]=(short)f2bf(a.w);
      fr[4]=(short)f2bf(b.x); fr[5]=(short)f2bf(b.y);
      fr[6]=(short)f2bf(b.z); fr[7]=(short)f2bf(b.w);
      afrag[kc] = fr;
    }
    f32x4 acc[8];
#pragma unroll
    for (int nt = 0; nt < 8; ++nt) acc[nt] = (f32x4)(0.0f);
#pragma unroll
    for (int kc = 0; kc < 4; ++kc)
#pragma unroll
      for (int nt = 0; nt < 8; ++nt)
        acc[nt] = __builtin_amdgcn_mfma_f32_16x16x32_bf16(afrag[kc], bfrag[nt][kc], acc[nt], 0, 0, 0);
#pragma unroll
    for (int nt = 0; nt < 4; ++nt)
#pragma unroll
      for (int j = 0; j < 4; ++j) {
        const unsigned int u = (unsigned)f2bf(acc[nt][j])
                             | ((unsigned)f2bf(acc[nt+4][j]) << 16);
        ipP[(long)(rb + lhi*4 + j)*64 + nt*16 + l15] = u;
      }
  }
}

// ---------------------------------------------------------------------------
// Phase 2: rnn13 — rnn12 + amdgpu_waves_per_eu(1,1)  (single change).
// r8-r12 post-mortem: VGPR stuck at 84 with weight loads re-executed in the
// loop (4 identical results, incl. named scalars + volatile asm). Cause:
// the backend scheduler/allocator targets HIGH OCCUPANCY by default and
// remats loop-invariant loads; launch_bounds only sets a min-waves budget,
// not the pressure target. amdgpu_waves_per_eu(1,1) pins max waves/EU = 1
// (physically true: 256 blocks = 1/CU) -> pressure target 512 VGPRs ->
// the 128 weight VGPRs can stay genuinely resident.
// ---------------------------------------------------------------------------
__global__ __attribute__((amdgpu_waves_per_eu(1, 1)))
__launch_bounds__(256) void rnn13(
    const unsigned int* __restrict__ ipP, const uint4* __restrict__ W4,
    const float* __restrict__ bin, const float* __restrict__ bh,
    float* __restrict__ out)
{
  __shared__ unsigned int hb[4][2][64];   // [wave][buf][64 h-pair uints]

  const int tid = threadIdx.x;
  const int w   = tid >> 6;            // wave = local row 0..3
  const int l   = tid & 63;
  const int row = blockIdx.x*4 + w;    // global batch row

  hb[w][0][l] = 0u;                    // h_0 = 0

  // 32 NAMED weight registers (16 chunks x {f=l, f=l+64}), coalesced loads.
#define WLD(i) \
  const uint4 wa##i = W4[(i)*128 + l]; \
  const uint4 wb##i = W4[(i)*128 + 64 + l];
  WLD(0)  WLD(1)  WLD(2)  WLD(3)  WLD(4)  WLD(5)  WLD(6)  WLD(7)
  WLD(8)  WLD(9)  WLD(10) WLD(11) WLD(12) WLD(13) WLD(14) WLD(15)
#undef WLD

  const float bias0 = bin[l]      + bh[l];
  const float bias1 = bin[l + 64] + bh[l + 64];
  __syncthreads();   // h0 visible (and weight loads drained once)

  // ip stream: uint pair {ip[row][s][l], ip[row][s][l+64]}; prefetch 2 deep
  const unsigned int* ipp = ipP + (size_t)row * SEQ * 64 + l;
  unsigned int ic = ipp[0];
  unsigned int in = ipp[64];

  float hf0 = 0.0f, hf1 = 0.0f;

  for (int s = 0; s < SEQ; ++s) {
    const int sp = (s + 2 < SEQ) ? s + 2 : SEQ - 1;
    const unsigned int pn = ipp[(size_t)sp * 64];

    const uint4* th = (const uint4*)&hb[w][s & 1][0];

    float a00 = bias0 + __uint_as_float(ic << 16);
    float a10 = bias1 + __uint_as_float(ic & 0xffff0000u);
    float a01 = 0.0f, a02 = 0.0f, a03 = 0.0f;
    float a11 = 0.0f, a12 = 0.0f, a13 = 0.0f;

    // 16 chunks: broadcast b128 h read + 8 fdot2, named temps (die fast)
#define STEP(i, K) { \
    const uint4 hc = th[i]; \
    a0##K = fd(hc.x, wa##i.x, a0##K); \
    a0##K = fd(hc.y, wa##i.y, a0##K); \
    a0##K = fd(hc.z, wa##i.z, a0##K); \
    a0##K = fd(hc.w, wa##i.w, a0##K); \
    a1##K = fd(hc.x, wb##i.x, a1##K); \
    a1##K = fd(hc.y, wb##i.y, a1##K); \
    a1##K = fd(hc.z, wb##i.z, a1##K); \
    a1##K = fd(hc.w, wb##i.w, a1##K); }
    STEP(0,0)  STEP(1,1)  STEP(2,2)  STEP(3,3)
    STEP(4,0)  STEP(5,1)  STEP(6,2)  STEP(7,3)
    STEP(8,0)  STEP(9,1)  STEP(10,2) STEP(11,3)
    STEP(12,0) STEP(13,1) STEP(14,2) STEP(15,3)
#undef STEP

    const float v0 = (a00 + a01) + (a02 + a03);
    const float v1 = (a10 + a11) + (a12 + a13);

    // tanh (proven path)
    const float e0 = __expf(2.0f * v0);
    hf0 = 1.0f - __fdividef(2.0f, e0 + 1.0f);
    const float e1 = __expf(2.0f * v1);
    hf1 = 1.0f - __fdividef(2.0f, e1 + 1.0f);

    // next h pair; intra-wave DS ordering, no barrier (r8-verified)
    hb[w][(s + 1) & 1][l] = packh2(hf0, hf1);

    ic = in;
    in = pn;
  }

  // L2 normalize: whole row in this wave (2 values/lane)
  float pj = hf0*hf0 + hf1*hf1;
#pragma unroll
  for (int off = 1; off < 64; off <<= 1) pj += __shfl_xor(pj, off, 64);
  const float inv = 1.0f / fmaxf(sqrtf(pj), 1e-12f);
  out[(size_t)row*EMB + l]      = hf0 * inv;
  out[(size_t)row*EMB + 64 + l] = hf1 * inv;
}

// ---------------------------------------------------------------------------
// Fallback (small ws): round-1 VALU recurrence (known-correct, no scratch).
// ---------------------------------------------------------------------------
__global__ __launch_bounds__(512) void rnn_fused(
    const int* __restrict__ xidx, const float* __restrict__ emb,
    const float* __restrict__ Win, const float* __restrict__ bin,
    const float* __restrict__ Wh,  const float* __restrict__ bh,
    float* __restrict__ out)
{
  __shared__ float h_lds[4][EMB];
  __shared__ float part[8][4][EMB];
  __shared__ float emb_lds[2][4][EMB];
  __shared__ int   x_lds[4][SEQ];
  __shared__ float red[8];

  const int t   = threadIdx.x;
  const int f0  = (t & 63) * 2;
  const int eg  = t >> 6;
  const int e0  = eg * 16;
  const int b0  = blockIdx.x * 4;
  const int row = t >> 7;
  const int ff  = t & 127;

  float wh0[16], wh1[16], wi0[16], wi1[16];
  {
    const float* p0 = Wh + f0*EMB + e0;
    const float* p1 = Wh + (f0+1)*EMB + e0;
    const float* q0 = Win + f0*EMB + e0;
    const float* q1 = Win + (f0+1)*EMB + e0;
#pragma unroll
    for (int q = 0; q < 4; ++q) {
      float4 a = ((const float4*)p0)[q];
      wh0[4*q+0]=a.x; wh0[4*q+1]=a.y; wh0[4*q+2]=a.z; wh0[4*q+3]=a.w;
      float4 b = ((const float4*)p1)[q];
      wh1[4*q+0]=b.x; wh1[4*q+1]=b.y; wh1[4*q+2]=b.z; wh1[4*q+3]=b.w;
      float4 c = ((const float4*)q0)[q];
      wi0[4*q+0]=c.x; wi0[4*q+1]=c.y; wi0[4*q+2]=c.z; wi0[4*q+3]=c.w;
      float4 d = ((const float4*)q1)[q];
      wi1[4*q+0]=d.x; wi1[4*q+1]=d.y; wi1[4*q+2]=d.z; wi1[4*q+3]=d.w;
    }
  }
  const float bc = bin[ff] + bh[ff];
  h_lds[row][ff] = 0.0f;
  for (int i = t; i < 4*SEQ; i += 512)
    x_lds[i / SEQ][i % SEQ] = xidx[(b0 + i/SEQ)*SEQ + (i % SEQ)];
  __syncthreads();
  emb_lds[0][row][ff] = emb[(long)x_lds[row][0]*EMB + ff];
  __syncthreads();

  int cur = 0;
  for (int s = 0; s < SEQ; ++s) {
    float nxt = 0.0f;
    if (s + 1 < SEQ) nxt = emb[(long)x_lds[row][s+1]*EMB + ff];
    float pa0[4], pa1[4];
#pragma unroll
    for (int rq = 0; rq < 4; ++rq) { pa0[rq] = 0.0f; pa1[rq] = 0.0f; }
#pragma unroll
    for (int rq = 0; rq < 4; ++rq) {
      const float4* hp  = (const float4*)&h_lds[rq][e0];
      const float4* epv = (const float4*)&emb_lds[cur][rq][e0];
#pragma unroll
      for (int q = 0; q < 4; ++q) {
        float4 hv = hp[q], ev = epv[q];
        pa0[rq] = fmaf(hv.x, wh0[4*q+0], pa0[rq]); pa0[rq] = fmaf(hv.y, wh0[4*q+1], pa0[rq]);
        pa0[rq] = fmaf(hv.z, wh0[4*q+2], pa0[rq]); pa0[rq] = fmaf(hv.w, wh0[4*q+3], pa0[rq]);
        pa1[rq] = fmaf(hv.x, wh1[4*q+0], pa1[rq]); pa1[rq] = fmaf(hv.y, wh1[4*q+1], pa1[rq]);
        pa1[rq] = fmaf(hv.z, wh1[4*q+2], pa1[rq]); pa1[rq] = fmaf(hv.w, wh1[4*q+3], pa1[rq]);
        pa0[rq] = fmaf(ev.x, wi0[4*q+0], pa0[rq]); pa0[rq] = fmaf(ev.y, wi0[4*q+1], pa0[rq]);
        pa0[rq] = fmaf(ev.z, wi0[4*q+2], pa0[rq]); pa0[rq] = fmaf(ev.w, wi0[4*q+3], pa0[rq]);
        pa1[rq] = fmaf(ev.x, wi1[4*q+0], pa1[rq]); pa1[rq] = fmaf(ev.y, wi1[4*q+1], pa1[rq]);
        pa1[rq] = fmaf(ev.z, wi1[4*q+2], pa1[rq]); pa1[rq] = fmaf(ev.w, wi1[4*q+3], pa1[rq]);
      }
    }
#pragma unroll
    for (int rq = 0; rq < 4; ++rq) {
      part[eg][rq][f0]   = pa0[rq];
      part[eg][rq][f0+1] = pa1[rq];
    }
    __syncthreads();
    float acc = bc;
#pragma unroll
    for (int g = 0; g < 8; ++g) acc += part[g][row][ff];
    float hn = tanhf(acc);
    if (s + 1 < SEQ) emb_lds[cur ^ 1][row][ff] = nxt;
    h_lds[row][ff] = hn;
    __syncthreads();
    cur ^= 1;
  }
  float hv = h_lds[row][ff];
  float sq = hv * hv;
#pragma unroll
  for (int off = 32; off > 0; off >>= 1) sq += __shfl_xor(sq, off, 64);
  if ((t & 63) == 0) red[t >> 6] = sq;
  __syncthreads();
  float nrm = sqrtf(red[row*2] + red[row*2 + 1]);
  out[(b0 + row)*EMB + ff] = hv / fmaxf(nrm, 1e-12f);
}

// ---------------------------------------------------------------------------
extern "C" void kernel_launch(void* const* d_in, const int* in_sizes, int n_in,
                              void* d_out, int out_size, void* d_ws, size_t ws_size,
                              hipStream_t stream) {
  const int*   x    = (const int*)  d_in[0];
  const float* emb  = (const float*)d_in[1];
  const float* Win  = (const float*)d_in[2];
  const float* bin  = (const float*)d_in[3];
  const float* Wh   = (const float*)d_in[4];
  const float* bh   = (const float*)d_in[5];
  float* out = (float*)d_out;

  const size_t ip_bytes = (size_t)BATCH * SEQ * 64 * sizeof(unsigned int); // 52.4 MB
  const size_t wb_bytes = (size_t)EMB * EMB * sizeof(unsigned short);      // 32 KB
  const size_t w4_bytes = (size_t)16 * 128 * sizeof(uint4);                // 32 KB
  const size_t need     = ip_bytes + wb_bytes + w4_bytes;
  if (ws_size >= need) {
    unsigned int*   ipP = (unsigned int*)d_ws;
    unsigned short* Wb  = (unsigned short*)((char*)d_ws + ip_bytes);
    uint4*          W4  = (uint4*)((char*)d_ws + ip_bytes + wb_bytes);
    cvt_bf16<<<(EMB*EMB + 255)/256, 256, 0, stream>>>(Win, Wb, EMB*EMB);
    cvt_w4<<<8, 256, 0, stream>>>(Wh, W4);
    proj2<<<(BATCH*SEQ)/128, 256, 0, stream>>>(x, emb, Wb, ipP);
    rnn13<<<BATCH/4, 256, 0, stream>>>(ipP, W4, bin, bh, out);
  } else {
    rnn_fused<<<BATCH/4, 512, 0, stream>>>(x, emb, Win, bin, Wh, bh, out);
  }
}